// Round 10
// baseline (380.423 us; speedup 1.0000x reference)
//
#include <hip/hip_runtime.h>
#include <math.h>
#include <stdint.h>

#define SEQ 1029
#define BATCH 8
#define M_TOT (BATCH * SEQ)   /* 8232 */
#define M_PAD 8320            /* 65 * 128 */
#define NCHUNK 17             /* 16 x 64 feature keys + 1 chunk of 5 special keys */

typedef float floatx4 __attribute__((ext_vector_type(4)));
typedef __bf16 bf16x8 __attribute__((ext_vector_type(8)));

__device__ __forceinline__ unsigned short f2bf(float f) {
  union { float f; unsigned u; } v; v.f = f;
  unsigned r = v.u + 0x7fffu + ((v.u >> 16) & 1u);
  return (unsigned short)(r >> 16);
}
__device__ __forceinline__ float bf2f(unsigned short h) {
  union { unsigned u; float f; } v; v.u = ((unsigned)h) << 16;
  return v.f;
}
__device__ __forceinline__ float bf_lo(unsigned u) { union { unsigned x; float f; } v; v.x = u << 16; return v.f; }
__device__ __forceinline__ float bf_hi(unsigned u) { union { unsigned x; float f; } v; v.x = u & 0xffff0000u; return v.f; }

__device__ __forceinline__ float wave_sum(float v) {
#pragma unroll
  for (int off = 32; off > 0; off >>= 1) v += __shfl_xor(v, off, 64);
  return v;
}
__device__ __forceinline__ float wave_max(float v) {
#pragma unroll
  for (int off = 32; off > 0; off >>= 1) v = fmaxf(v, __shfl_xor(v, off, 64));
  return v;
}

/* fast GELU: A&S 7.1.26 erf (abs err < 1.5e-7) — error far below bf16 rounding */
__device__ __forceinline__ float fast_gelu(float v) {
  const float ax = fabsf(v) * 0.70710678118654752f;
  const float t = __builtin_amdgcn_rcpf(1.0f + 0.3275911f * ax);
  const float poly = ((((1.061405429f * t - 1.453152027f) * t + 1.421413741f) * t
                       - 0.284496736f) * t + 0.254829592f) * t;
  const float er = 1.0f - poly * __expf(-ax * ax);
  return 0.5f * v * (1.0f + copysignf(er, v));
}

/* async global -> LDS, 16B per lane (DMA writes lds base + lane*16) */
__device__ __forceinline__ void gload16(const unsigned short* g, unsigned short* l) {
  __builtin_amdgcn_global_load_lds(
      (const __attribute__((address_space(1))) unsigned int*)g,
      (__attribute__((address_space(3))) unsigned int*)l, 16, 0, 0);
}

template <int C>
__device__ __forceinline__ void vwait() {
  if constexpr (C == 0) asm volatile("s_waitcnt vmcnt(0)" ::: "memory");
  else if constexpr (C == 3) asm volatile("s_waitcnt vmcnt(3)" ::: "memory");
  else if constexpr (C == 4) asm volatile("s_waitcnt vmcnt(4)" ::: "memory");
  else asm volatile("s_waitcnt vmcnt(8)" ::: "memory");
}

/* ---------------- fused prep: all weights fp32 -> bf16, plus zero-fill pad rows ---------------- */
#define NQ_QKV 442368
#define NQ_OUT 147456
#define NQ_W1  589824
#define NQ_W2  589824
#define NQ_PAD 8448   /* (M_PAD-M_TOT)*768/8 ushort4 quads */
__global__ void convert_all(const float4* __restrict__ inw, const float4* __restrict__ outw,
                            const float4* __restrict__ w1, const float4* __restrict__ w2,
                            ushort4* __restrict__ wqkv, ushort4* __restrict__ wout,
                            ushort4* __restrict__ w1b, ushort4* __restrict__ w2b,
                            ushort4* __restrict__ xw_pad, ushort4* __restrict__ attn_pad) {
  const int i = blockIdx.x * 256 + threadIdx.x;
  const float4* src; ushort4* dst; int off;
  if (i < NQ_QKV) { src = inw; dst = wqkv; off = i; }
  else if (i < NQ_QKV + NQ_OUT) { src = outw; dst = wout; off = i - NQ_QKV; }
  else if (i < NQ_QKV + NQ_OUT + NQ_W1) { src = w1; dst = w1b; off = i - NQ_QKV - NQ_OUT; }
  else if (i < NQ_QKV + NQ_OUT + NQ_W1 + NQ_W2) { src = w2; dst = w2b; off = i - NQ_QKV - NQ_OUT - NQ_W1; }
  else {
    const int j = i - (NQ_QKV + NQ_OUT + NQ_W1 + NQ_W2);
    const ushort4 z = {0, 0, 0, 0};
    if (j < NQ_PAD) { xw_pad[j] = z; attn_pad[j] = z; }
    return;
  }
  const float4 v = src[off];
  ushort4 o;
  o.x = f2bf(v.x); o.y = f2bf(v.y); o.z = f2bf(v.z); o.w = f2bf(v.w);
  dst[off] = o;
}
#define NQ_ALL (NQ_QKV + NQ_OUT + NQ_W1 + NQ_W2 + NQ_PAD)

/* ---------------- LN1: feature tokens (x<64, transpose + LN) and ctx/reg rows (x==64) ---------------- */
__global__ __launch_bounds__(256) void ln1_all(const float* __restrict__ x,
                                               const float* __restrict__ ctx,
                                               const float* __restrict__ regs,
                                               const float* __restrict__ g,
                                               const float* __restrict__ bta,
                                               unsigned short* __restrict__ xw) {
  __shared__ float tile[768 * 17];  /* [c][hw], padded stride 17 */
  const int b = blockIdx.y;
  const int t = threadIdx.x;
  const int wave = t >> 6, lane = t & 63;

  if (blockIdx.x == 64) {
    for (int s = wave; s < 5; s += 4) {
      const float* src = (s == 0) ? (ctx + (size_t)b * 768)
                                  : (regs + ((size_t)b * 4 + (s - 1)) * 768);
      float vals[12], sm = 0.f, ss = 0.f;
#pragma unroll
      for (int i = 0; i < 12; i++) {
        const float v = src[lane + 64 * i];
        vals[i] = v; sm += v; ss += v * v;
      }
      sm = wave_sum(sm); ss = wave_sum(ss);
      const float mu = sm * (1.0f / 768.0f);
      const float var = ss * (1.0f / 768.0f) - mu * mu;
      const float rs = rsqrtf(var + 1e-5f);
      unsigned short* orow = xw + (size_t)(b * SEQ + s) * 768;
#pragma unroll
      for (int i = 0; i < 12; i++) {
        const int c = lane + 64 * i;
        orow[c] = f2bf((vals[i] - mu) * rs * g[c] + bta[c]);
      }
    }
    return;
  }

  const int hw0 = blockIdx.x * 16;
  const float* xb = x + (size_t)b * 768 * 1024;
  const int cl = t >> 4, hl = t & 15;
  for (int it = 0; it < 48; it++) {
    const int c = it * 16 + cl;
    tile[c * 17 + hl] = xb[(size_t)c * 1024 + hw0 + hl];
  }
  __syncthreads();
  for (int tk = wave; tk < 16; tk += 4) {
    float vals[12], s = 0.f, ss = 0.f;
#pragma unroll
    for (int i = 0; i < 12; i++) {
      const float v = tile[(lane + 64 * i) * 17 + tk];
      vals[i] = v; s += v; ss += v * v;
    }
    s = wave_sum(s); ss = wave_sum(ss);
    const float mu = s * (1.0f / 768.0f);
    const float var = ss * (1.0f / 768.0f) - mu * mu;
    const float rs = rsqrtf(var + 1e-5f);
    const int row = b * SEQ + 5 + hw0 + tk;
    unsigned short* orow = xw + (size_t)row * 768;
#pragma unroll
    for (int i = 0; i < 12; i++) {
      const int c = lane + 64 * i;
      orow[c] = f2bf((vals[i] - mu) * rs * g[c] + bta[c]);
    }
  }
}

#define BM 128
#define BN 128
#define BK 32

/* ---------------- gemm_bt (128x128, 4 waves): NBUF-ring pipeline.
   NBUF=2 + (256,4): 32 KiB LDS, 4 blocks/CU, drain wait, TLP hides the
   stall (proven best for big-grid GEMMs, rounds 6/7).
   NBUF=4 + (256,2): 64 KiB, deep counted-vmcnt (grid-limited N=768). ---------------- */
template <int EPI, int K, int N, int NBUF>
__global__ __launch_bounds__(256, NBUF == 2 ? 4 : 2) void gemm_bt(
    const unsigned short* __restrict__ A,
    const unsigned short* __restrict__ W,
    const float* __restrict__ bias,
    const unsigned short* __restrict__ residb,
    const float* __restrict__ residf,
    float* __restrict__ outf,
    unsigned short* __restrict__ outb) {
  __shared__ alignas(16) unsigned short As[NBUF][BM * BK];
  __shared__ alignas(16) unsigned short Ws[NBUF][BN * BK];
  const int t = threadIdx.x;
  const int wave = t >> 6, lane = t & 63;
  const int quad = lane >> 4, l16 = lane & 15;
  const int wm = (wave & 1) * 64, wn = (wave >> 1) * 64;

  constexpr int GX = N / BN;
  constexpr int NWG = GX * (M_PAD / BM);
  constexpr int Q8 = NWG / 8, R8 = NWG % 8;
  const int flat = blockIdx.y * GX + blockIdx.x;
  const int xcd = flat & 7, idx = flat >> 3;
  const int wgid = (xcd < R8 ? xcd * (Q8 + 1) : R8 * (Q8 + 1) + (xcd - R8) * Q8) + idx;
  const int tileM = (wgid / GX) * BM;
  const int tileN = (wgid % GX) * BN;

  const int rl = lane >> 2;
  const int kc8 = ((lane & 3) ^ ((rl >> 1) & 3)) * 8;
  const unsigned short* Ag = A + (size_t)(tileM + wave * 16 + rl) * K;
  const unsigned short* Wg = W + (size_t)(tileN + wave * 16 + rl) * K;
  const int ldst = wave * 512 + lane * 8;
  const int koff = ((quad ^ ((l16 >> 1) & 3)) * 8);

  const floatx4 zero4 = {0.f, 0.f, 0.f, 0.f};
  floatx4 acc[4][4];
#pragma unroll
  for (int i = 0; i < 4; i++)
#pragma unroll
    for (int j = 0; j < 4; j++) acc[i][j] = zero4;

  auto dma = [&](int k0, int buf) {
    gload16(Ag + k0 + kc8, &As[buf][0] + ldst);
    gload16(Ag + (size_t)64 * K + k0 + kc8, &As[buf][0] + ldst + 2048);
    gload16(Wg + k0 + kc8, &Ws[buf][0] + ldst);
    gload16(Wg + (size_t)64 * K + k0 + kc8, &Ws[buf][0] + ldst + 2048);
  };
  auto compute = [&](int buf) {
    bf16x8 af[4], wf[4];
#pragma unroll
    for (int i = 0; i < 4; i++)
      af[i] = *(const bf16x8*)(&As[buf][0] + (wm + i * 16 + l16) * BK + koff);
#pragma unroll
    for (int j = 0; j < 4; j++)
      wf[j] = *(const bf16x8*)(&Ws[buf][0] + (wn + j * 16 + l16) * BK + koff);
#pragma unroll
    for (int i = 0; i < 4; i++)
#pragma unroll
      for (int j = 0; j < 4; j++)
        acc[i][j] = __builtin_amdgcn_mfma_f32_16x16x32_bf16(af[i], wf[j], acc[i][j], 0, 0, 0);
  };

  constexpr int NSTEP = K / BK;
  constexpr int PF = NBUF - 1;
#pragma unroll
  for (int p = 0; p < PF; ++p) dma(p * BK, p);

  int cb = 0, db = PF % NBUF;
#pragma unroll 1
  for (int i = 0; i < NSTEP - PF; ++i) {
    vwait<4 * (NBUF - 2)>();
    __builtin_amdgcn_s_barrier();
    __builtin_amdgcn_sched_barrier(0);
    dma((i + PF) * BK, db);
    db = (db + 1 == NBUF) ? 0 : db + 1;
    compute(cb);
    cb = (cb + 1 == NBUF) ? 0 : cb + 1;
  }
  if constexpr (NBUF == 4) {
    vwait<8>(); __builtin_amdgcn_s_barrier(); __builtin_amdgcn_sched_barrier(0);
    compute(cb); cb = (cb + 1 == NBUF) ? 0 : cb + 1;
    vwait<4>(); __builtin_amdgcn_s_barrier(); __builtin_amdgcn_sched_barrier(0);
    compute(cb); cb = (cb + 1 == NBUF) ? 0 : cb + 1;
  }
  vwait<0>(); __builtin_amdgcn_s_barrier(); __builtin_amdgcn_sched_barrier(0);
  compute(cb);

#pragma unroll
  for (int i = 0; i < 4; i++) {
    const int mbase = tileM + wm + i * 16 + quad * 4;
#pragma unroll
    for (int j = 0; j < 4; j++) {
      const int n = tileN + wn + j * 16 + l16;
      const float bv = bias[n];
#pragma unroll
      for (int r = 0; r < 4; r++) {
        const size_t idx2 = (size_t)(mbase + r) * N + n;
        float v = acc[i][j][r] + bv;
        if constexpr (EPI == 0) {
          outb[idx2] = f2bf(v);
        } else if constexpr (EPI == 1) {
          outf[idx2] = v + bf2f(residb[idx2]);
        } else {
          outb[idx2] = f2bf(fast_gelu(v));
        }
      }
    }
  }
}

/* ---------------- gemm_bn256 (128x256 tile, 8 waves/512 thr, wave-tile 64x64):
   FF1. __launch_bounds__(512,4) -> 2 blocks/CU (wave-limited), VGPR cap 128,
   no spill. NBUF=3 ring (72 KiB LDS — free, occupancy stays 2 blocks/CU):
   counted vmcnt(3) keeps one full K-phase of loads in flight across the
   barrier -> ~2x the load->use latency cover vs the 2-buffer drain. ---------------- */
template <int EPI, int K, int N>
__global__ __launch_bounds__(512, 4) void gemm_bn256(
    const unsigned short* __restrict__ A,
    const unsigned short* __restrict__ W,
    const float* __restrict__ bias,
    unsigned short* __restrict__ outb) {
  __shared__ alignas(16) unsigned short As[3][128 * BK];   /* 3 x 8 KiB */
  __shared__ alignas(16) unsigned short Ws[3][256 * BK];   /* 3 x 16 KiB */
  const int t = threadIdx.x;
  const int wave = t >> 6, lane = t & 63;
  const int quad = lane >> 4, l16 = lane & 15;
  const int wm = (wave & 1) * 64, wn = (wave >> 1) * 64;   /* 2M x 4N waves */

  constexpr int GX = N / 256;
  constexpr int NWG = GX * (M_PAD / BM);
  constexpr int Q8 = NWG / 8, R8 = NWG % 8;
  const int flat = blockIdx.y * GX + blockIdx.x;
  const int xcd = flat & 7, idx = flat >> 3;
  const int wgid = (xcd < R8 ? xcd * (Q8 + 1) : R8 * (Q8 + 1) + (xcd - R8) * Q8) + idx;
  const int tileM = (wgid / GX) * BM;
  const int tileN = (wgid % GX) * 256;

  const int rl = lane >> 2;
  const int kc8 = ((lane & 3) ^ ((rl >> 1) & 3)) * 8;
  const unsigned short* Ag = A + (size_t)(tileM + wave * 16 + rl) * K;
  const unsigned short* Wg = W + (size_t)(tileN + wave * 16 + rl) * K;
  const int ldst = t * 8;                                  /* 512 thr x 16B = 8 KiB */
  const int koff = ((quad ^ ((l16 >> 1) & 3)) * 8);

  const floatx4 zero4 = {0.f, 0.f, 0.f, 0.f};
  floatx4 acc[4][4];
#pragma unroll
  for (int i = 0; i < 4; i++)
#pragma unroll
    for (int j = 0; j < 4; j++) acc[i][j] = zero4;

  /* A: 128x32 = 8 KiB -> 1 gload16/thread; W: 256x32 = 16 KiB -> 2 */
  auto dma = [&](int k0, int buf) {
    gload16(Ag + k0 + kc8, &As[buf][0] + ldst);
    gload16(Wg + k0 + kc8, &Ws[buf][0] + ldst);
    gload16(Wg + (size_t)128 * K + k0 + kc8, &Ws[buf][0] + ldst + 4096);
  };
  auto compute = [&](int buf) {
    bf16x8 af[4], wf[4];
#pragma unroll
    for (int i = 0; i < 4; i++)
      af[i] = *(const bf16x8*)(&As[buf][0] + (wm + i * 16 + l16) * BK + koff);
#pragma unroll
    for (int j = 0; j < 4; j++)
      wf[j] = *(const bf16x8*)(&Ws[buf][0] + (wn + j * 16 + l16) * BK + koff);
#pragma unroll
    for (int i = 0; i < 4; i++)
#pragma unroll
      for (int j = 0; j < 4; j++)
        acc[i][j] = __builtin_amdgcn_mfma_f32_16x16x32_bf16(af[i], wf[j], acc[i][j], 0, 0, 0);
  };

  constexpr int NSTEP = K / BK;

  /* prologue: 2 phases in flight (6 loads) */
  dma(0, 0);
  dma(BK, 1);

  int cb = 0, db = 2;
#pragma unroll 1
  for (int i = 0; i < NSTEP - 2; ++i) {
    vwait<3>();                    /* dma(i) landed; dma(i+1)'s 3 loads in flight */
    __builtin_amdgcn_s_barrier();
    __builtin_amdgcn_sched_barrier(0);
    dma((i + 2) * BK, db);         /* buf db == (i-1)%3: readers passed the barrier */
    db = (db + 1 == 3) ? 0 : db + 1;
    compute(cb);
    cb = (cb + 1 == 3) ? 0 : cb + 1;
  }
  vwait<3>(); __builtin_amdgcn_s_barrier(); __builtin_amdgcn_sched_barrier(0);
  compute(cb); cb = (cb + 1 == 3) ? 0 : cb + 1;
  vwait<0>(); __builtin_amdgcn_s_barrier(); __builtin_amdgcn_sched_barrier(0);
  compute(cb);

#pragma unroll
  for (int i = 0; i < 4; i++) {
    const int mbase = tileM + wm + i * 16 + quad * 4;
#pragma unroll
    for (int j = 0; j < 4; j++) {
      const int n = tileN + wn + j * 16 + l16;
      const float bv = bias[n];
#pragma unroll
      for (int r = 0; r < 4; r++) {
        const size_t idx2 = (size_t)(mbase + r) * N + n;
        float v = acc[i][j][r] + bv;
        if constexpr (EPI == 0) outb[idx2] = f2bf(v);
        else                    outb[idx2] = f2bf(fast_gelu(v));
      }
    }
  }
}

/* ---------------- FF2 GEMM + h1 residual + fused output scatter (round-7 proven). ---------------- */
__global__ __launch_bounds__(256, 2) void gemm_ff2scat(
    const unsigned short* __restrict__ A,
    const unsigned short* __restrict__ W,
    const float* __restrict__ bias,
    const float* __restrict__ residf,
    float* __restrict__ dout) {
  constexpr int K = 3072, N = 768, NBUF = 4;
  __shared__ union {
    struct {
      alignas(16) unsigned short As[NBUF][BM * BK];
      alignas(16) unsigned short Ws[NBUF][BN * BK];
    } ring;
    float tr[128][133];
  } sm;
  const int t = threadIdx.x;
  const int wave = t >> 6, lane = t & 63;
  const int quad = lane >> 4, l16 = lane & 15;
  const int wm = (wave & 1) * 64, wn = (wave >> 1) * 64;

  constexpr int GX = N / BN;
  constexpr int NWG = GX * (M_PAD / BM);
  constexpr int Q8 = NWG / 8, R8 = NWG % 8;
  const int flat = blockIdx.y * GX + blockIdx.x;
  const int xcd = flat & 7, idx = flat >> 3;
  const int wgid = (xcd < R8 ? xcd * (Q8 + 1) : R8 * (Q8 + 1) + (xcd - R8) * Q8) + idx;
  const int tileM = (wgid / GX) * BM;
  const int tileN = (wgid % GX) * BN;

  const int rl = lane >> 2;
  const int kc8 = ((lane & 3) ^ ((rl >> 1) & 3)) * 8;
  const unsigned short* Ag = A + (size_t)(tileM + wave * 16 + rl) * K;
  const unsigned short* Wg = W + (size_t)(tileN + wave * 16 + rl) * K;
  const int ldst = wave * 512 + lane * 8;
  const int koff = ((quad ^ ((l16 >> 1) & 3)) * 8);

  const floatx4 zero4 = {0.f, 0.f, 0.f, 0.f};
  floatx4 acc[4][4];
#pragma unroll
  for (int i = 0; i < 4; i++)
#pragma unroll
    for (int j = 0; j < 4; j++) acc[i][j] = zero4;

  auto dma = [&](int k0, int buf) {
    gload16(Ag + k0 + kc8, &sm.ring.As[buf][0] + ldst);
    gload16(Ag + (size_t)64 * K + k0 + kc8, &sm.ring.As[buf][0] + ldst + 2048);
    gload16(Wg + k0 + kc8, &sm.ring.Ws[buf][0] + ldst);
    gload16(Wg + (size_t)64 * K + k0 + kc8, &sm.ring.Ws[buf][0] + ldst + 2048);
  };
  auto compute = [&](int buf) {
    bf16x8 af[4], wf[4];
#pragma unroll
    for (int i = 0; i < 4; i++)
      af[i] = *(const bf16x8*)(&sm.ring.As[buf][0] + (wm + i * 16 + l16) * BK + koff);
#pragma unroll
    for (int j = 0; j < 4; j++)
      wf[j] = *(const bf16x8*)(&sm.ring.Ws[buf][0] + (wn + j * 16 + l16) * BK + koff);
#pragma unroll
    for (int i = 0; i < 4; i++)
#pragma unroll
      for (int j = 0; j < 4; j++)
        acc[i][j] = __builtin_amdgcn_mfma_f32_16x16x32_bf16(af[i], wf[j], acc[i][j], 0, 0, 0);
  };

  constexpr int NSTEP = K / BK;
  constexpr int PF = NBUF - 1;
#pragma unroll
  for (int p = 0; p < PF; ++p) dma(p * BK, p);

  int cb = 0, db = PF % NBUF;
#pragma unroll 1
  for (int i = 0; i < NSTEP - PF; ++i) {
    vwait<8>();
    __builtin_amdgcn_s_barrier();
    __builtin_amdgcn_sched_barrier(0);
    dma((i + PF) * BK, db);
    db = (db + 1 == NBUF) ? 0 : db + 1;
    compute(cb);
    cb = (cb + 1 == NBUF) ? 0 : cb + 1;
  }
  vwait<8>(); __builtin_amdgcn_s_barrier(); __builtin_amdgcn_sched_barrier(0);
  compute(cb); cb = (cb + 1 == NBUF) ? 0 : cb + 1;
  vwait<4>(); __builtin_amdgcn_s_barrier(); __builtin_amdgcn_sched_barrier(0);
  compute(cb); cb = (cb + 1 == NBUF) ? 0 : cb + 1;
  vwait<0>(); __builtin_amdgcn_s_barrier(); __builtin_amdgcn_sched_barrier(0);
  compute(cb);

  __syncthreads();
#pragma unroll
  for (int i = 0; i < 4; i++) {
    const int mb = wm + i * 16 + quad * 4;
#pragma unroll
    for (int j = 0; j < 4; j++) {
      const int n_loc = wn + j * 16 + l16;
      const float bv = bias[tileN + n_loc];
#pragma unroll
      for (int r = 0; r < 4; r++) {
        const int m_loc = mb + r;
        const float v = acc[i][j][r] + bv +
                        residf[(size_t)(tileM + m_loc) * N + tileN + n_loc];
        sm.tr[m_loc][n_loc] = v;
      }
    }
  }
  __syncthreads();

  const int b0 = tileM / SEQ;
  const int bnd = (b0 + 1) * SEQ - tileM;
#pragma unroll
  for (int rh = 0; rh < 2; rh++) {
    const int row_loc = rh * 64 + lane;
    const int row = tileM + row_loc;
    const int bb = b0 + (row_loc >= bnd ? 1 : 0);
    const int s = row - bb * SEQ;
    const bool ok = row < M_TOT;
    for (int cc = 0; cc < 32; cc++) {
      const int c_loc = wave * 32 + cc;
      const int c = tileN + c_loc;
      const float v = sm.tr[row_loc][c_loc];
      if (ok) {
        if (s >= 5)
          dout[(size_t)bb * 786432 + (size_t)c * 1024 + (s - 5)] = v;
        else if (s == 0)
          dout[6291456 + (size_t)bb * 768 + c] = v;
        else
          dout[6297600 + ((size_t)bb * 4 + (s - 1)) * 768 + c] = v;
      }
    }
  }
}

/* ---------------- attention: feature rows (x<256) + special-row split-K phase 1 (x>=256) ---------------- */
__global__ __launch_bounds__(256) void attn_all(const unsigned short* __restrict__ qkv,
                                                unsigned short* __restrict__ attn,
                                                float* __restrict__ part) {
  __shared__ float kk[5][64];
  __shared__ float vv[5][64];
  __shared__ float sc[5][64];
  __shared__ float mArr[5], lArr[5];
  __shared__ float og[4][320];
  const int h = blockIdx.y, b = blockIdx.z;
  const int t = threadIdx.x;
  const size_t base = (size_t)b * SEQ;
  const int wave = t >> 6, lane = t & 63;

  if (blockIdx.x < 256) {
    for (int i = t; i < 320; i += 256) {
      const int j = i >> 6, dd = i & 63;
      const size_t rb = (base + j) * 2304 + (size_t)h * 64 + dd;
      kk[j][dd] = bf2f(qkv[rb + 768]);
      vv[j][dd] = bf2f(qkv[rb + 1536]);
    }
    __syncthreads();
    const int s = 5 + blockIdx.x * 4 + wave;
    const size_t row = (base + s) * 2304 + (size_t)h * 64;
    const float q = bf2f(qkv[row + lane]);
    const float kself = bf2f(qkv[row + 768 + lane]);
    const float vself = bf2f(qkv[row + 1536 + lane]);
    float scr[6];
#pragma unroll
    for (int j = 0; j < 5; j++) scr[j] = wave_sum(q * kk[j][lane]) * 0.125f;
    scr[5] = wave_sum(q * kself) * 0.125f;
    float mx = scr[0];
#pragma unroll
    for (int j = 1; j < 6; j++) mx = fmaxf(mx, scr[j]);
    float den = 0.f, e[6];
#pragma unroll
    for (int j = 0; j < 6; j++) { e[j] = expf(scr[j] - mx); den += e[j]; }
    const float inv = 1.0f / den;
    float o = 0.f;
#pragma unroll
    for (int j = 0; j < 5; j++) o += e[j] * vv[j][lane];
    o += e[5] * vself;
    attn[(base + s) * 768 + (size_t)h * 64 + lane] = f2bf(o * inv);
    return;
  }

  const int c = blockIdx.x - 256;
  const int kbase = (c < 16) ? (5 + 64 * c) : 0;
  const int nvalid = (c < 16) ? 64 : 5;

  for (int i = t; i < 320; i += 256)
    kk[i >> 6][i & 63] = bf2f(qkv[(base + (i >> 6)) * 2304 + (size_t)h * 64 + (i & 63)]);
  __syncthreads();

  const int keyloc = t >> 2, dc = t & 3;
  const int key = kbase + keyloc;
  const unsigned short* krow = qkv + (base + key) * 2304 + 768 + (size_t)h * 64;
  const uint4 k0 = *(const uint4*)(krow + dc * 8);
  const uint4 k1 = *(const uint4*)(krow + dc * 8 + 32);
  float kf[16];
  {
    const unsigned ku[8] = {k0.x, k0.y, k0.z, k0.w, k1.x, k1.y, k1.z, k1.w};
#pragma unroll
    for (int j = 0; j < 8; j++) { kf[2 * j] = bf_lo(ku[j]); kf[2 * j + 1] = bf_hi(ku[j]); }
  }
#pragma unroll
  for (int q = 0; q < 5; q++) {
    const float* qp = kk[q];
    float d0 = 0.f;
#pragma unroll
    for (int j = 0; j < 8; j++) d0 += qp[dc * 8 + j] * kf[j];
#pragma unroll
    for (int j = 0; j < 8; j++) d0 += qp[dc * 8 + 32 + j] * kf[8 + j];
    d0 += __shfl_xor(d0, 1, 64);
    d0 += __shfl_xor(d0, 2, 64);
    if (dc == 0) sc[q][keyloc] = (keyloc < nvalid) ? d0 * 0.125f : -1e30f;
  }
  __syncthreads();

  for (int q = wave; q < 5; q += 4) {
    const float v = sc[q][lane];
    const float m = wave_max(v);
    const float e = expf(v - m);
    sc[q][lane] = e;
    const float l = wave_sum(e);
    if (lane == 0) { mArr[q] = m; lArr[q] = l; }
  }
  __syncthreads();

  const int d = t & 63, g = t >> 6;
  float o[5] = {0.f, 0.f, 0.f, 0.f, 0.f};
  for (int i = 0; i < 16; i++) {
    const int kl = g * 16 + i;
    const float v = bf2f(qkv[(base + kbase + kl) * 2304 + 1536 + (size_t)h * 64 + d]);
#pragma unroll
    for (int q = 0; q < 5; q++) o[q] += sc[q][kl] * v;
  }
#pragma unroll
  for (int q = 0; q < 5; q++) og[g][q * 64 + d] = o[q];
  __syncthreads();

  float* pw = part + (size_t)((b * 12 + h) * NCHUNK + c) * 5 * 66;
  for (int i = t; i < 320; i += 256) {
    const int q = i >> 6, dd = i & 63;
    pw[q * 66 + 2 + dd] = og[0][i] + og[1][i] + og[2][i] + og[3][i];
    if (dd == 0) { pw[q * 66] = mArr[q]; pw[q * 66 + 1] = lArr[q]; }
  }
}

/* ---------------- split-K phase 2: online-merge 17 chunk partials ---------------- */
__global__ __launch_bounds__(64) void attn_comb(const float* __restrict__ part,
                                                unsigned short* __restrict__ attn) {
  const int qi = blockIdx.x, h = blockIdx.y, b = blockIdx.z;
  const int d = threadIdx.x;
  float M = -3e38f, L = 0.f, o = 0.f;
  for (int c = 0; c < NCHUNK; c++) {
    const float* p = part + ((size_t)((b * 12 + h) * NCHUNK + c) * 5 + qi) * 66;
    const float mc = p[0], lc = p[1], oc = p[2 + d];
    if (mc > M) {
      const float s = expf(M - mc);
      L = L * s + lc; o = o * s + oc; M = mc;
    } else {
      const float w = expf(mc - M);
      L += lc * w; o += oc * w;
    }
  }
  attn[((size_t)b * SEQ + qi) * 768 + (size_t)h * 64 + d] = f2bf(o / L);
}

/* ---------------- LN2: wave per row over h1 (fp32) -> bf16 ---------------- */
__global__ __launch_bounds__(256) void ln2_kernel(const float* __restrict__ h1,
                                                  const float* __restrict__ g,
                                                  const float* __restrict__ bta,
                                                  unsigned short* __restrict__ out) {
  const int row = blockIdx.x * 4 + (threadIdx.x >> 6);
  const int lane = threadIdx.x & 63;
  const float* r = h1 + (size_t)row * 768;
  float vals[12], sm = 0.f, ss = 0.f;
#pragma unroll
  for (int i = 0; i < 12; i++) {
    const float v = r[lane + 64 * i];
    vals[i] = v; sm += v; ss += v * v;
  }
  sm = wave_sum(sm); ss = wave_sum(ss);
  const float mu = sm * (1.0f / 768.0f);
  const float var = ss * (1.0f / 768.0f) - mu * mu;
  const float rs = rsqrtf(var + 1e-5f);
  unsigned short* orow = out + (size_t)row * 768;
#pragma unroll
  for (int i = 0; i < 12; i++) {
    const int c = lane + 64 * i;
    orow[c] = f2bf((vals[i] - mu) * rs * g[c] + bta[c]);
  }
}

/* ---------------- host orchestration ---------------- */
extern "C" void kernel_launch(void* const* d_in, const int* in_sizes, int n_in,
                              void* d_out, int out_size, void* d_ws, size_t ws_size,
                              hipStream_t stream) {
  const float* x    = (const float*)d_in[0];
  const float* ctx  = (const float*)d_in[1];
  const float* regs = (const float*)d_in[2];
  const float* inw  = (const float*)d_in[3];
  const float* inb  = (const float*)d_in[4];
  const float* outw = (const float*)d_in[5];
  const float* outbi= (const float*)d_in[6];
  const float* ln1g = (const float*)d_in[7];
  const float* ln1b = (const float*)d_in[8];
  const float* ln2g = (const float*)d_in[9];
  const float* ln2b = (const float*)d_in[10];
  const float* w1   = (const float*)d_in[11];
  const float* b1   = (const float*)d_in[12];
  const float* w2   = (const float*)d_in[13];
  const float* b2   = (const float*)d_in[14];

  char* ws = (char*)d_ws;
  unsigned short* wqkv_b = (unsigned short*)(ws + 0);         /* 2304x768 bf16 */
  unsigned short* wout_b = (unsigned short*)(ws + 3538944);   /* 768x768 */
  unsigned short* w1_b   = (unsigned short*)(ws + 4718592);   /* 3072x768 */
  unsigned short* w2_b   = (unsigned short*)(ws + 9437184);   /* 768x3072 */
  unsigned short* xw_b   = (unsigned short*)(ws + 14155776);  /* M_PAD x 768 bf16 */
  unsigned short* ln2o_b = (unsigned short*)(ws + 26935296);  /* M_PAD x 768 bf16 */
  float*          h1_f   = (float*)(ws + 39714816);           /* M_PAD x 768 f32 */
  unsigned short* qkv_b  = (unsigned short*)(ws + 65273856);  /* M_PAD x 2304 bf16 */
  unsigned short* attn_b = (unsigned short*)(ws + 103612416); /* M_PAD x 768 bf16 */
  unsigned short* ffm_b  = (unsigned short*)(ws + 65273856);  /* alias qkv+attn (dead then) */
  float*          part_f = (float*)(ws + 116391936);          /* dedicated tail, 2.15 MB */
  float* dout = (float*)d_out;

  /* fused prep: weights -> bf16, pad rows -> 0 */
  convert_all<<<(NQ_ALL + 255) / 256, 256, 0, stream>>>(
      (const float4*)inw, (const float4*)outw, (const float4*)w1, (const float4*)w2,
      (ushort4*)wqkv_b, (ushort4*)wout_b, (ushort4*)w1_b, (ushort4*)w2_b,
      (ushort4*)(xw_b + (size_t)M_TOT * 768), (ushort4*)(attn_b + (size_t)M_TOT * 768));

  /* LN1 (+ implicit transpose of x) + special rows */
  ln1_all<<<dim3(65, 8), 256, 0, stream>>>(x, ctx, regs, ln1g, ln1b, xw_b);

  /* QKV: 128x128, NBUF=2, (256,4) -> 4 blocks/CU (round-7 proven for big grids) */
  gemm_bt<0, 768, 2304, 2><<<dim3(2304 / BN, M_PAD / BM), 256, 0, stream>>>(
      xw_b, wqkv_b, inb, nullptr, nullptr, nullptr, qkv_b);

  /* attention: feat + special partials, then merge */
  attn_all<<<dim3(256 + NCHUNK, 12, 8), 256, 0, stream>>>(qkv_b, attn_b, part_f);
  attn_comb<<<dim3(5, 12, 8), 64, 0, stream>>>(part_f, attn_b);

  /* out-proj + residual -> h1 (fp32): grid-limited (390) -> NBUF=4 deep */
  gemm_bt<1, 768, 768, 4><<<dim3(768 / BN, M_PAD / BM), 256, 0, stream>>>(
      attn_b, wout_b, outbi, xw_b, nullptr, h1_f, nullptr);

  /* LN2 */
  ln2_kernel<<<M_PAD / 4, 256, 0, stream>>>(h1_f, ln2g, ln2b, ln2o_b);

  /* FF1 + fast GELU: 128x256, 8 waves, NBUF=3 counted-vmcnt (780 blocks, 2/CU) */
  gemm_bn256<2, 768, 3072><<<dim3(3072 / 256, M_PAD / BM), 512, 0, stream>>>(
      ln2o_b, w1_b, b1, ffm_b);

  /* FF2 + h1 residual + fused transpose-scatter straight to dout */
  gemm_ff2scat<<<dim3(768 / BN, M_PAD / BM), 256, 0, stream>>>(
      ffm_b, w2_b, b2, h1_f, dout);
}

// Round 11
// 349.278 us; speedup vs baseline: 1.0892x; 1.0892x over previous
//
#include <hip/hip_runtime.h>
#include <math.h>
#include <stdint.h>

#define SEQ 1029
#define BATCH 8
#define M_TOT (BATCH * SEQ)   /* 8232 */
#define M_PAD 8320            /* 65 * 128 */
#define NCHUNK 17             /* 16 x 64 feature keys + 1 chunk of 5 special keys */

typedef float floatx4 __attribute__((ext_vector_type(4)));
typedef __bf16 bf16x8 __attribute__((ext_vector_type(8)));

__device__ __forceinline__ unsigned short f2bf(float f) {
  union { float f; unsigned u; } v; v.f = f;
  unsigned r = v.u + 0x7fffu + ((v.u >> 16) & 1u);
  return (unsigned short)(r >> 16);
}
__device__ __forceinline__ float bf2f(unsigned short h) {
  union { unsigned u; float f; } v; v.u = ((unsigned)h) << 16;
  return v.f;
}
__device__ __forceinline__ float bf_lo(unsigned u) { union { unsigned x; float f; } v; v.x = u << 16; return v.f; }
__device__ __forceinline__ float bf_hi(unsigned u) { union { unsigned x; float f; } v; v.x = u & 0xffff0000u; return v.f; }

__device__ __forceinline__ float wave_sum(float v) {
#pragma unroll
  for (int off = 32; off > 0; off >>= 1) v += __shfl_xor(v, off, 64);
  return v;
}
__device__ __forceinline__ float wave_max(float v) {
#pragma unroll
  for (int off = 32; off > 0; off >>= 1) v = fmaxf(v, __shfl_xor(v, off, 64));
  return v;
}

/* fast GELU: A&S 7.1.26 erf (abs err < 1.5e-7) — error far below bf16 rounding */
__device__ __forceinline__ float fast_gelu(float v) {
  const float ax = fabsf(v) * 0.70710678118654752f;
  const float t = __builtin_amdgcn_rcpf(1.0f + 0.3275911f * ax);
  const float poly = ((((1.061405429f * t - 1.453152027f) * t + 1.421413741f) * t
                       - 0.284496736f) * t + 0.254829592f) * t;
  const float er = 1.0f - poly * __expf(-ax * ax);
  return 0.5f * v * (1.0f + copysignf(er, v));
}

/* async global -> LDS, 16B per lane (DMA writes lds base + lane*16) */
__device__ __forceinline__ void gload16(const unsigned short* g, unsigned short* l) {
  __builtin_amdgcn_global_load_lds(
      (const __attribute__((address_space(1))) unsigned int*)g,
      (__attribute__((address_space(3))) unsigned int*)l, 16, 0, 0);
}

template <int C>
__device__ __forceinline__ void vwait() {
  if constexpr (C == 0) asm volatile("s_waitcnt vmcnt(0)" ::: "memory");
  else if constexpr (C == 3) asm volatile("s_waitcnt vmcnt(3)" ::: "memory");
  else if constexpr (C == 4) asm volatile("s_waitcnt vmcnt(4)" ::: "memory");
  else asm volatile("s_waitcnt vmcnt(8)" ::: "memory");
}

/* ---------------- fused prep: all weights fp32 -> bf16, plus zero-fill pad rows ---------------- */
#define NQ_QKV 442368
#define NQ_OUT 147456
#define NQ_W1  589824
#define NQ_W2  589824
#define NQ_PAD 8448   /* (M_PAD-M_TOT)*768/8 ushort4 quads */
__global__ void convert_all(const float4* __restrict__ inw, const float4* __restrict__ outw,
                            const float4* __restrict__ w1, const float4* __restrict__ w2,
                            ushort4* __restrict__ wqkv, ushort4* __restrict__ wout,
                            ushort4* __restrict__ w1b, ushort4* __restrict__ w2b,
                            ushort4* __restrict__ xw_pad, ushort4* __restrict__ attn_pad) {
  const int i = blockIdx.x * 256 + threadIdx.x;
  const float4* src; ushort4* dst; int off;
  if (i < NQ_QKV) { src = inw; dst = wqkv; off = i; }
  else if (i < NQ_QKV + NQ_OUT) { src = outw; dst = wout; off = i - NQ_QKV; }
  else if (i < NQ_QKV + NQ_OUT + NQ_W1) { src = w1; dst = w1b; off = i - NQ_QKV - NQ_OUT; }
  else if (i < NQ_QKV + NQ_OUT + NQ_W1 + NQ_W2) { src = w2; dst = w2b; off = i - NQ_QKV - NQ_OUT - NQ_W1; }
  else {
    const int j = i - (NQ_QKV + NQ_OUT + NQ_W1 + NQ_W2);
    const ushort4 z = {0, 0, 0, 0};
    if (j < NQ_PAD) { xw_pad[j] = z; attn_pad[j] = z; }
    return;
  }
  const float4 v = src[off];
  ushort4 o;
  o.x = f2bf(v.x); o.y = f2bf(v.y); o.z = f2bf(v.z); o.w = f2bf(v.w);
  dst[off] = o;
}
#define NQ_ALL (NQ_QKV + NQ_OUT + NQ_W1 + NQ_W2 + NQ_PAD)

/* ---------------- LN1: feature tokens (x<64, transpose + LN) and ctx/reg rows (x==64) ---------------- */
__global__ __launch_bounds__(256) void ln1_all(const float* __restrict__ x,
                                               const float* __restrict__ ctx,
                                               const float* __restrict__ regs,
                                               const float* __restrict__ g,
                                               const float* __restrict__ bta,
                                               unsigned short* __restrict__ xw) {
  __shared__ float tile[768 * 17];  /* [c][hw], padded stride 17 */
  const int b = blockIdx.y;
  const int t = threadIdx.x;
  const int wave = t >> 6, lane = t & 63;

  if (blockIdx.x == 64) {
    for (int s = wave; s < 5; s += 4) {
      const float* src = (s == 0) ? (ctx + (size_t)b * 768)
                                  : (regs + ((size_t)b * 4 + (s - 1)) * 768);
      float vals[12], sm = 0.f, ss = 0.f;
#pragma unroll
      for (int i = 0; i < 12; i++) {
        const float v = src[lane + 64 * i];
        vals[i] = v; sm += v; ss += v * v;
      }
      sm = wave_sum(sm); ss = wave_sum(ss);
      const float mu = sm * (1.0f / 768.0f);
      const float var = ss * (1.0f / 768.0f) - mu * mu;
      const float rs = rsqrtf(var + 1e-5f);
      unsigned short* orow = xw + (size_t)(b * SEQ + s) * 768;
#pragma unroll
      for (int i = 0; i < 12; i++) {
        const int c = lane + 64 * i;
        orow[c] = f2bf((vals[i] - mu) * rs * g[c] + bta[c]);
      }
    }
    return;
  }

  const int hw0 = blockIdx.x * 16;
  /* float4 global loads: 3072 float4 per block, 12 per thread, fully coalesced */
  const float4* xb4 = (const float4*)x + (size_t)b * 196608 + (hw0 >> 2);
#pragma unroll
  for (int it = 0; it < 12; it++) {
    const int idx = it * 256 + t;
    const int c = idx >> 2, f4 = idx & 3;
    const float4 v = xb4[(size_t)c * 256 + f4];
    float* dst = &tile[c * 17 + f4 * 4];
    dst[0] = v.x; dst[1] = v.y; dst[2] = v.z; dst[3] = v.w;
  }
  __syncthreads();
  for (int tk = wave; tk < 16; tk += 4) {
    float vals[12], s = 0.f, ss = 0.f;
#pragma unroll
    for (int i = 0; i < 12; i++) {
      const float v = tile[(lane + 64 * i) * 17 + tk];
      vals[i] = v; s += v; ss += v * v;
    }
    s = wave_sum(s); ss = wave_sum(ss);
    const float mu = s * (1.0f / 768.0f);
    const float var = ss * (1.0f / 768.0f) - mu * mu;
    const float rs = rsqrtf(var + 1e-5f);
    const int row = b * SEQ + 5 + hw0 + tk;
    unsigned short* orow = xw + (size_t)row * 768;
#pragma unroll
    for (int i = 0; i < 12; i++) {
      const int c = lane + 64 * i;
      orow[c] = f2bf((vals[i] - mu) * rs * g[c] + bta[c]);
    }
  }
}

#define BM 128
#define BN 128
#define BK 32

/* ---------------- gemm_bt (128x128, 4 waves): NBUF-ring pipeline.
   NBUF=2 + (256,4): 32 KiB LDS, 4 blocks/CU, drain wait, TLP hides the
   stall (proven best for big-grid GEMMs, rounds 6/7).
   NBUF=4 + (256,2): 64 KiB, deep counted-vmcnt (grid-limited N=768). ---------------- */
template <int EPI, int K, int N, int NBUF>
__global__ __launch_bounds__(256, NBUF == 2 ? 4 : 2) void gemm_bt(
    const unsigned short* __restrict__ A,
    const unsigned short* __restrict__ W,
    const float* __restrict__ bias,
    const unsigned short* __restrict__ residb,
    const float* __restrict__ residf,
    float* __restrict__ outf,
    unsigned short* __restrict__ outb) {
  __shared__ alignas(16) unsigned short As[NBUF][BM * BK];
  __shared__ alignas(16) unsigned short Ws[NBUF][BN * BK];
  const int t = threadIdx.x;
  const int wave = t >> 6, lane = t & 63;
  const int quad = lane >> 4, l16 = lane & 15;
  const int wm = (wave & 1) * 64, wn = (wave >> 1) * 64;

  constexpr int GX = N / BN;
  constexpr int NWG = GX * (M_PAD / BM);
  constexpr int Q8 = NWG / 8, R8 = NWG % 8;
  const int flat = blockIdx.y * GX + blockIdx.x;
  const int xcd = flat & 7, idx = flat >> 3;
  const int wgid = (xcd < R8 ? xcd * (Q8 + 1) : R8 * (Q8 + 1) + (xcd - R8) * Q8) + idx;
  const int tileM = (wgid / GX) * BM;
  const int tileN = (wgid % GX) * BN;

  const int rl = lane >> 2;
  const int kc8 = ((lane & 3) ^ ((rl >> 1) & 3)) * 8;
  const unsigned short* Ag = A + (size_t)(tileM + wave * 16 + rl) * K;
  const unsigned short* Wg = W + (size_t)(tileN + wave * 16 + rl) * K;
  const int ldst = wave * 512 + lane * 8;
  const int koff = ((quad ^ ((l16 >> 1) & 3)) * 8);

  const floatx4 zero4 = {0.f, 0.f, 0.f, 0.f};
  floatx4 acc[4][4];
#pragma unroll
  for (int i = 0; i < 4; i++)
#pragma unroll
    for (int j = 0; j < 4; j++) acc[i][j] = zero4;

  auto dma = [&](int k0, int buf) {
    gload16(Ag + k0 + kc8, &As[buf][0] + ldst);
    gload16(Ag + (size_t)64 * K + k0 + kc8, &As[buf][0] + ldst + 2048);
    gload16(Wg + k0 + kc8, &Ws[buf][0] + ldst);
    gload16(Wg + (size_t)64 * K + k0 + kc8, &Ws[buf][0] + ldst + 2048);
  };
  auto compute = [&](int buf) {
    bf16x8 af[4], wf[4];
#pragma unroll
    for (int i = 0; i < 4; i++)
      af[i] = *(const bf16x8*)(&As[buf][0] + (wm + i * 16 + l16) * BK + koff);
#pragma unroll
    for (int j = 0; j < 4; j++)
      wf[j] = *(const bf16x8*)(&Ws[buf][0] + (wn + j * 16 + l16) * BK + koff);
#pragma unroll
    for (int i = 0; i < 4; i++)
#pragma unroll
      for (int j = 0; j < 4; j++)
        acc[i][j] = __builtin_amdgcn_mfma_f32_16x16x32_bf16(af[i], wf[j], acc[i][j], 0, 0, 0);
  };

  constexpr int NSTEP = K / BK;
  constexpr int PF = NBUF - 1;
#pragma unroll
  for (int p = 0; p < PF; ++p) dma(p * BK, p);

  int cb = 0, db = PF % NBUF;
#pragma unroll 1
  for (int i = 0; i < NSTEP - PF; ++i) {
    vwait<4 * (NBUF - 2)>();
    __builtin_amdgcn_s_barrier();
    __builtin_amdgcn_sched_barrier(0);
    dma((i + PF) * BK, db);
    db = (db + 1 == NBUF) ? 0 : db + 1;
    compute(cb);
    cb = (cb + 1 == NBUF) ? 0 : cb + 1;
  }
  if constexpr (NBUF == 4) {
    vwait<8>(); __builtin_amdgcn_s_barrier(); __builtin_amdgcn_sched_barrier(0);
    compute(cb); cb = (cb + 1 == NBUF) ? 0 : cb + 1;
    vwait<4>(); __builtin_amdgcn_s_barrier(); __builtin_amdgcn_sched_barrier(0);
    compute(cb); cb = (cb + 1 == NBUF) ? 0 : cb + 1;
  }
  vwait<0>(); __builtin_amdgcn_s_barrier(); __builtin_amdgcn_sched_barrier(0);
  compute(cb);

#pragma unroll
  for (int i = 0; i < 4; i++) {
    const int mbase = tileM + wm + i * 16 + quad * 4;
#pragma unroll
    for (int j = 0; j < 4; j++) {
      const int n = tileN + wn + j * 16 + l16;
      const float bv = bias[n];
#pragma unroll
      for (int r = 0; r < 4; r++) {
        const size_t idx2 = (size_t)(mbase + r) * N + n;
        float v = acc[i][j][r] + bv;
        if constexpr (EPI == 0) {
          outb[idx2] = f2bf(v);
        } else if constexpr (EPI == 1) {
          outf[idx2] = v + bf2f(residb[idx2]);
        } else {
          outb[idx2] = f2bf(fast_gelu(v));
        }
      }
    }
  }
}

/* ---------------- gemm_bn256 (128x256 tile, 8 waves/512 thr, wave-tile 64x64):
   FF1. (512,4) -> 2 blocks/CU, VGPR cap 128, no spill. NBUF=3 ring (72 KiB,
   free at this occupancy): counted vmcnt(3) keeps one full K-phase of loads
   in flight across the barrier. ---------------- */
template <int EPI, int K, int N>
__global__ __launch_bounds__(512, 4) void gemm_bn256(
    const unsigned short* __restrict__ A,
    const unsigned short* __restrict__ W,
    const float* __restrict__ bias,
    unsigned short* __restrict__ outb) {
  __shared__ alignas(16) unsigned short As[3][128 * BK];   /* 3 x 8 KiB */
  __shared__ alignas(16) unsigned short Ws[3][256 * BK];   /* 3 x 16 KiB */
  const int t = threadIdx.x;
  const int wave = t >> 6, lane = t & 63;
  const int quad = lane >> 4, l16 = lane & 15;
  const int wm = (wave & 1) * 64, wn = (wave >> 1) * 64;   /* 2M x 4N waves */

  constexpr int GX = N / 256;
  constexpr int NWG = GX * (M_PAD / BM);
  constexpr int Q8 = NWG / 8, R8 = NWG % 8;
  const int flat = blockIdx.y * GX + blockIdx.x;
  const int xcd = flat & 7, idx = flat >> 3;
  const int wgid = (xcd < R8 ? xcd * (Q8 + 1) : R8 * (Q8 + 1) + (xcd - R8) * Q8) + idx;
  const int tileM = (wgid / GX) * BM;
  const int tileN = (wgid % GX) * 256;

  const int rl = lane >> 2;
  const int kc8 = ((lane & 3) ^ ((rl >> 1) & 3)) * 8;
  const unsigned short* Ag = A + (size_t)(tileM + wave * 16 + rl) * K;
  const unsigned short* Wg = W + (size_t)(tileN + wave * 16 + rl) * K;
  const int ldst = t * 8;                                  /* 512 thr x 16B = 8 KiB */
  const int koff = ((quad ^ ((l16 >> 1) & 3)) * 8);

  const floatx4 zero4 = {0.f, 0.f, 0.f, 0.f};
  floatx4 acc[4][4];
#pragma unroll
  for (int i = 0; i < 4; i++)
#pragma unroll
    for (int j = 0; j < 4; j++) acc[i][j] = zero4;

  /* A: 128x32 = 8 KiB -> 1 gload16/thread; W: 256x32 = 16 KiB -> 2 */
  auto dma = [&](int k0, int buf) {
    gload16(Ag + k0 + kc8, &As[buf][0] + ldst);
    gload16(Wg + k0 + kc8, &Ws[buf][0] + ldst);
    gload16(Wg + (size_t)128 * K + k0 + kc8, &Ws[buf][0] + ldst + 4096);
  };
  auto compute = [&](int buf) {
    bf16x8 af[4], wf[4];
#pragma unroll
    for (int i = 0; i < 4; i++)
      af[i] = *(const bf16x8*)(&As[buf][0] + (wm + i * 16 + l16) * BK + koff);
#pragma unroll
    for (int j = 0; j < 4; j++)
      wf[j] = *(const bf16x8*)(&Ws[buf][0] + (wn + j * 16 + l16) * BK + koff);
#pragma unroll
    for (int i = 0; i < 4; i++)
#pragma unroll
      for (int j = 0; j < 4; j++)
        acc[i][j] = __builtin_amdgcn_mfma_f32_16x16x32_bf16(af[i], wf[j], acc[i][j], 0, 0, 0);
  };

  constexpr int NSTEP = K / BK;

  dma(0, 0);
  dma(BK, 1);

  int cb = 0, db = 2;
#pragma unroll 1
  for (int i = 0; i < NSTEP - 2; ++i) {
    vwait<3>();
    __builtin_amdgcn_s_barrier();
    __builtin_amdgcn_sched_barrier(0);
    dma((i + 2) * BK, db);
    db = (db + 1 == 3) ? 0 : db + 1;
    compute(cb);
    cb = (cb + 1 == 3) ? 0 : cb + 1;
  }
  vwait<3>(); __builtin_amdgcn_s_barrier(); __builtin_amdgcn_sched_barrier(0);
  compute(cb); cb = (cb + 1 == 3) ? 0 : cb + 1;
  vwait<0>(); __builtin_amdgcn_s_barrier(); __builtin_amdgcn_sched_barrier(0);
  compute(cb);

#pragma unroll
  for (int i = 0; i < 4; i++) {
    const int mbase = tileM + wm + i * 16 + quad * 4;
#pragma unroll
    for (int j = 0; j < 4; j++) {
      const int n = tileN + wn + j * 16 + l16;
      const float bv = bias[n];
#pragma unroll
      for (int r = 0; r < 4; r++) {
        const size_t idx2 = (size_t)(mbase + r) * N + n;
        float v = acc[i][j][r] + bv;
        if constexpr (EPI == 0) outb[idx2] = f2bf(v);
        else                    outb[idx2] = f2bf(fast_gelu(v));
      }
    }
  }
}

/* ---------------- FF2 GEMM + h1 residual + fused output scatter (round-7 proven). ---------------- */
__global__ __launch_bounds__(256, 2) void gemm_ff2scat(
    const unsigned short* __restrict__ A,
    const unsigned short* __restrict__ W,
    const float* __restrict__ bias,
    const float* __restrict__ residf,
    float* __restrict__ dout) {
  constexpr int K = 3072, N = 768, NBUF = 4;
  __shared__ union {
    struct {
      alignas(16) unsigned short As[NBUF][BM * BK];
      alignas(16) unsigned short Ws[NBUF][BN * BK];
    } ring;
    float tr[128][133];
  } sm;
  const int t = threadIdx.x;
  const int wave = t >> 6, lane = t & 63;
  const int quad = lane >> 4, l16 = lane & 15;
  const int wm = (wave & 1) * 64, wn = (wave >> 1) * 64;

  constexpr int GX = N / BN;
  constexpr int NWG = GX * (M_PAD / BM);
  constexpr int Q8 = NWG / 8, R8 = NWG % 8;
  const int flat = blockIdx.y * GX + blockIdx.x;
  const int xcd = flat & 7, idx = flat >> 3;
  const int wgid = (xcd < R8 ? xcd * (Q8 + 1) : R8 * (Q8 + 1) + (xcd - R8) * Q8) + idx;
  const int tileM = (wgid / GX) * BM;
  const int tileN = (wgid % GX) * BN;

  const int rl = lane >> 2;
  const int kc8 = ((lane & 3) ^ ((rl >> 1) & 3)) * 8;
  const unsigned short* Ag = A + (size_t)(tileM + wave * 16 + rl) * K;
  const unsigned short* Wg = W + (size_t)(tileN + wave * 16 + rl) * K;
  const int ldst = wave * 512 + lane * 8;
  const int koff = ((quad ^ ((l16 >> 1) & 3)) * 8);

  const floatx4 zero4 = {0.f, 0.f, 0.f, 0.f};
  floatx4 acc[4][4];
#pragma unroll
  for (int i = 0; i < 4; i++)
#pragma unroll
    for (int j = 0; j < 4; j++) acc[i][j] = zero4;

  auto dma = [&](int k0, int buf) {
    gload16(Ag + k0 + kc8, &sm.ring.As[buf][0] + ldst);
    gload16(Ag + (size_t)64 * K + k0 + kc8, &sm.ring.As[buf][0] + ldst + 2048);
    gload16(Wg + k0 + kc8, &sm.ring.Ws[buf][0] + ldst);
    gload16(Wg + (size_t)64 * K + k0 + kc8, &sm.ring.Ws[buf][0] + ldst + 2048);
  };
  auto compute = [&](int buf) {
    bf16x8 af[4], wf[4];
#pragma unroll
    for (int i = 0; i < 4; i++)
      af[i] = *(const bf16x8*)(&sm.ring.As[buf][0] + (wm + i * 16 + l16) * BK + koff);
#pragma unroll
    for (int j = 0; j < 4; j++)
      wf[j] = *(const bf16x8*)(&sm.ring.Ws[buf][0] + (wn + j * 16 + l16) * BK + koff);
#pragma unroll
    for (int i = 0; i < 4; i++)
#pragma unroll
      for (int j = 0; j < 4; j++)
        acc[i][j] = __builtin_amdgcn_mfma_f32_16x16x32_bf16(af[i], wf[j], acc[i][j], 0, 0, 0);
  };

  constexpr int NSTEP = K / BK;
  constexpr int PF = NBUF - 1;
#pragma unroll
  for (int p = 0; p < PF; ++p) dma(p * BK, p);

  int cb = 0, db = PF % NBUF;
#pragma unroll 1
  for (int i = 0; i < NSTEP - PF; ++i) {
    vwait<8>();
    __builtin_amdgcn_s_barrier();
    __builtin_amdgcn_sched_barrier(0);
    dma((i + PF) * BK, db);
    db = (db + 1 == NBUF) ? 0 : db + 1;
    compute(cb);
    cb = (cb + 1 == NBUF) ? 0 : cb + 1;
  }
  vwait<8>(); __builtin_amdgcn_s_barrier(); __builtin_amdgcn_sched_barrier(0);
  compute(cb); cb = (cb + 1 == NBUF) ? 0 : cb + 1;
  vwait<4>(); __builtin_amdgcn_s_barrier(); __builtin_amdgcn_sched_barrier(0);
  compute(cb); cb = (cb + 1 == NBUF) ? 0 : cb + 1;
  vwait<0>(); __builtin_amdgcn_s_barrier(); __builtin_amdgcn_sched_barrier(0);
  compute(cb);

  __syncthreads();
#pragma unroll
  for (int i = 0; i < 4; i++) {
    const int mb = wm + i * 16 + quad * 4;
#pragma unroll
    for (int j = 0; j < 4; j++) {
      const int n_loc = wn + j * 16 + l16;
      const float bv = bias[tileN + n_loc];
#pragma unroll
      for (int r = 0; r < 4; r++) {
        const int m_loc = mb + r;
        const float v = acc[i][j][r] + bv +
                        residf[(size_t)(tileM + m_loc) * N + tileN + n_loc];
        sm.tr[m_loc][n_loc] = v;
      }
    }
  }
  __syncthreads();

  const int b0 = tileM / SEQ;
  const int bnd = (b0 + 1) * SEQ - tileM;
#pragma unroll
  for (int rh = 0; rh < 2; rh++) {
    const int row_loc = rh * 64 + lane;
    const int row = tileM + row_loc;
    const int bb = b0 + (row_loc >= bnd ? 1 : 0);
    const int s = row - bb * SEQ;
    const bool ok = row < M_TOT;
    for (int cc = 0; cc < 32; cc++) {
      const int c_loc = wave * 32 + cc;
      const int c = tileN + c_loc;
      const float v = sm.tr[row_loc][c_loc];
      if (ok) {
        if (s >= 5)
          dout[(size_t)bb * 786432 + (size_t)c * 1024 + (s - 5)] = v;
        else if (s == 0)
          dout[6291456 + (size_t)bb * 768 + c] = v;
        else
          dout[6297600 + ((size_t)bb * 4 + (s - 1)) * 768 + c] = v;
      }
    }
  }
}

/* ---------------- attention: feature rows (x<32, 32 rows/block, 16-lane-group
   parallel softmax: 6 shfl/row vs 36) + special-row split-K phase 1 (x>=32) ---------------- */
__global__ __launch_bounds__(256) void attn_all(const unsigned short* __restrict__ qkv,
                                                unsigned short* __restrict__ attn,
                                                float* __restrict__ part) {
  __shared__ float kk[5][64];
  __shared__ float vv[5][64];
  __shared__ float sc[5][64];
  __shared__ float mArr[5], lArr[5];
  __shared__ float og[4][320];
  const int h = blockIdx.y, b = blockIdx.z;
  const int t = threadIdx.x;
  const size_t base = (size_t)b * SEQ;
  const int wave = t >> 6, lane = t & 63;

  if (blockIdx.x < 32) {
    for (int i = t; i < 320; i += 256) {
      const int j = i >> 6, dd = i & 63;
      const size_t rb = (base + j) * 2304 + (size_t)h * 64 + dd;
      kk[j][dd] = bf2f(qkv[rb + 768]);
      vv[j][dd] = bf2f(qkv[rb + 1536]);
    }
    __syncthreads();
    const int g = lane >> 4, l16 = lane & 15;
    const int d4 = l16 * 4;
    /* shared-key fragments for this lane's 4 dims (register-resident) */
    float kkf[5][4], vvf[5][4];
#pragma unroll
    for (int j = 0; j < 5; j++) {
      const float4 kv = *(const float4*)&kk[j][d4];
      kkf[j][0] = kv.x; kkf[j][1] = kv.y; kkf[j][2] = kv.z; kkf[j][3] = kv.w;
      const float4 vw = *(const float4*)&vv[j][d4];
      vvf[j][0] = vw.x; vvf[j][1] = vw.y; vvf[j][2] = vw.z; vvf[j][3] = vw.w;
    }
#pragma unroll
    for (int it = 0; it < 2; it++) {
      const int s = 5 + blockIdx.x * 32 + wave * 8 + it * 4 + g;
      const unsigned short* qrow = qkv + (base + s) * 2304 + (size_t)h * 64 + d4;
      const ushort4 qv = *(const ushort4*)qrow;
      const ushort4 kv = *(const ushort4*)(qrow + 768);
      const ushort4 sv = *(const ushort4*)(qrow + 1536);
      const float qf[4] = {bf2f(qv.x), bf2f(qv.y), bf2f(qv.z), bf2f(qv.w)};
      const float kf[4] = {bf2f(kv.x), bf2f(kv.y), bf2f(kv.z), bf2f(kv.w)};
      const float vf[4] = {bf2f(sv.x), bf2f(sv.y), bf2f(sv.z), bf2f(sv.w)};
      float sc6[6];
#pragma unroll
      for (int j = 0; j < 5; j++)
        sc6[j] = qf[0] * kkf[j][0] + qf[1] * kkf[j][1] + qf[2] * kkf[j][2] + qf[3] * kkf[j][3];
      sc6[5] = qf[0] * kf[0] + qf[1] * kf[1] + qf[2] * kf[2] + qf[3] * kf[3];
#pragma unroll
      for (int j = 0; j < 6; j++) {
#pragma unroll
        for (int off = 8; off > 0; off >>= 1) sc6[j] += __shfl_xor(sc6[j], off, 64);
        sc6[j] *= 0.125f;
      }
      float mx = sc6[0];
#pragma unroll
      for (int j = 1; j < 6; j++) mx = fmaxf(mx, sc6[j]);
      float den = 0.f, e[6];
#pragma unroll
      for (int j = 0; j < 6; j++) { e[j] = expf(sc6[j] - mx); den += e[j]; }
      const float inv = 1.0f / den;
      ushort4 ov;
      float o[4];
#pragma unroll
      for (int d = 0; d < 4; d++) {
        float a = e[5] * vf[d];
#pragma unroll
        for (int j = 0; j < 5; j++) a += e[j] * vvf[j][d];
        o[d] = a * inv;
      }
      ov.x = f2bf(o[0]); ov.y = f2bf(o[1]); ov.z = f2bf(o[2]); ov.w = f2bf(o[3]);
      *(ushort4*)(attn + (base + s) * 768 + (size_t)h * 64 + d4) = ov;
    }
    return;
  }

  const int c = blockIdx.x - 32;
  const int kbase = (c < 16) ? (5 + 64 * c) : 0;
  const int nvalid = (c < 16) ? 64 : 5;

  for (int i = t; i < 320; i += 256)
    kk[i >> 6][i & 63] = bf2f(qkv[(base + (i >> 6)) * 2304 + (size_t)h * 64 + (i & 63)]);
  __syncthreads();

  const int keyloc = t >> 2, dc = t & 3;
  const int key = kbase + keyloc;
  const unsigned short* krow = qkv + (base + key) * 2304 + 768 + (size_t)h * 64;
  const uint4 k0 = *(const uint4*)(krow + dc * 8);
  const uint4 k1 = *(const uint4*)(krow + dc * 8 + 32);
  float kf[16];
  {
    const unsigned ku[8] = {k0.x, k0.y, k0.z, k0.w, k1.x, k1.y, k1.z, k1.w};
#pragma unroll
    for (int j = 0; j < 8; j++) { kf[2 * j] = bf_lo(ku[j]); kf[2 * j + 1] = bf_hi(ku[j]); }
  }
#pragma unroll
  for (int q = 0; q < 5; q++) {
    const float* qp = kk[q];
    float d0 = 0.f;
#pragma unroll
    for (int j = 0; j < 8; j++) d0 += qp[dc * 8 + j] * kf[j];
#pragma unroll
    for (int j = 0; j < 8; j++) d0 += qp[dc * 8 + 32 + j] * kf[8 + j];
    d0 += __shfl_xor(d0, 1, 64);
    d0 += __shfl_xor(d0, 2, 64);
    if (dc == 0) sc[q][keyloc] = (keyloc < nvalid) ? d0 * 0.125f : -1e30f;
  }
  __syncthreads();

  for (int q = wave; q < 5; q += 4) {
    const float v = sc[q][lane];
    const float m = wave_max(v);
    const float e = expf(v - m);
    sc[q][lane] = e;
    const float l = wave_sum(e);
    if (lane == 0) { mArr[q] = m; lArr[q] = l; }
  }
  __syncthreads();

  const int d = t & 63, g2 = t >> 6;
  float o[5] = {0.f, 0.f, 0.f, 0.f, 0.f};
  for (int i = 0; i < 16; i++) {
    const int kl = g2 * 16 + i;
    const float v = bf2f(qkv[(base + kbase + kl) * 2304 + 1536 + (size_t)h * 64 + d]);
#pragma unroll
    for (int q = 0; q < 5; q++) o[q] += sc[q][kl] * v;
  }
#pragma unroll
  for (int q = 0; q < 5; q++) og[g2][q * 64 + d] = o[q];
  __syncthreads();

  float* pw = part + (size_t)((b * 12 + h) * NCHUNK + c) * 5 * 66;
  for (int i = t; i < 320; i += 256) {
    const int q = i >> 6, dd = i & 63;
    pw[q * 66 + 2 + dd] = og[0][i] + og[1][i] + og[2][i] + og[3][i];
    if (dd == 0) { pw[q * 66] = mArr[q]; pw[q * 66 + 1] = lArr[q]; }
  }
}

/* ---------------- split-K phase 2: online-merge 17 chunk partials ---------------- */
__global__ __launch_bounds__(64) void attn_comb(const float* __restrict__ part,
                                                unsigned short* __restrict__ attn) {
  const int qi = blockIdx.x, h = blockIdx.y, b = blockIdx.z;
  const int d = threadIdx.x;
  float M = -3e38f, L = 0.f, o = 0.f;
  for (int c = 0; c < NCHUNK; c++) {
    const float* p = part + ((size_t)((b * 12 + h) * NCHUNK + c) * 5 + qi) * 66;
    const float mc = p[0], lc = p[1], oc = p[2 + d];
    if (mc > M) {
      const float s = expf(M - mc);
      L = L * s + lc; o = o * s + oc; M = mc;
    } else {
      const float w = expf(mc - M);
      L += lc * w; o += oc * w;
    }
  }
  attn[((size_t)b * SEQ + qi) * 768 + (size_t)h * 64 + d] = f2bf(o / L);
}

/* ---------------- LN2: wave per row over h1 (fp32) -> bf16 ---------------- */
__global__ __launch_bounds__(256) void ln2_kernel(const float* __restrict__ h1,
                                                  const float* __restrict__ g,
                                                  const float* __restrict__ bta,
                                                  unsigned short* __restrict__ out) {
  const int row = blockIdx.x * 4 + (threadIdx.x >> 6);
  const int lane = threadIdx.x & 63;
  const float* r = h1 + (size_t)row * 768;
  float vals[12], sm = 0.f, ss = 0.f;
#pragma unroll
  for (int i = 0; i < 12; i++) {
    const float v = r[lane + 64 * i];
    vals[i] = v; sm += v; ss += v * v;
  }
  sm = wave_sum(sm); ss = wave_sum(ss);
  const float mu = sm * (1.0f / 768.0f);
  const float var = ss * (1.0f / 768.0f) - mu * mu;
  const float rs = rsqrtf(var + 1e-5f);
  unsigned short* orow = out + (size_t)row * 768;
#pragma unroll
  for (int i = 0; i < 12; i++) {
    const int c = lane + 64 * i;
    orow[c] = f2bf((vals[i] - mu) * rs * g[c] + bta[c]);
  }
}

/* ---------------- host orchestration ---------------- */
extern "C" void kernel_launch(void* const* d_in, const int* in_sizes, int n_in,
                              void* d_out, int out_size, void* d_ws, size_t ws_size,
                              hipStream_t stream) {
  const float* x    = (const float*)d_in[0];
  const float* ctx  = (const float*)d_in[1];
  const float* regs = (const float*)d_in[2];
  const float* inw  = (const float*)d_in[3];
  const float* inb  = (const float*)d_in[4];
  const float* outw = (const float*)d_in[5];
  const float* outbi= (const float*)d_in[6];
  const float* ln1g = (const float*)d_in[7];
  const float* ln1b = (const float*)d_in[8];
  const float* ln2g = (const float*)d_in[9];
  const float* ln2b = (const float*)d_in[10];
  const float* w1   = (const float*)d_in[11];
  const float* b1   = (const float*)d_in[12];
  const float* w2   = (const float*)d_in[13];
  const float* b2   = (const float*)d_in[14];

  char* ws = (char*)d_ws;
  unsigned short* wqkv_b = (unsigned short*)(ws + 0);         /* 2304x768 bf16 */
  unsigned short* wout_b = (unsigned short*)(ws + 3538944);   /* 768x768 */
  unsigned short* w1_b   = (unsigned short*)(ws + 4718592);   /* 3072x768 */
  unsigned short* w2_b   = (unsigned short*)(ws + 9437184);   /* 768x3072 */
  unsigned short* xw_b   = (unsigned short*)(ws + 14155776);  /* M_PAD x 768 bf16 */
  unsigned short* ln2o_b = (unsigned short*)(ws + 26935296);  /* M_PAD x 768 bf16 */
  float*          h1_f   = (float*)(ws + 39714816);           /* M_PAD x 768 f32 */
  unsigned short* qkv_b  = (unsigned short*)(ws + 65273856);  /* M_PAD x 2304 bf16 */
  unsigned short* attn_b = (unsigned short*)(ws + 103612416); /* M_PAD x 768 bf16 */
  unsigned short* ffm_b  = (unsigned short*)(ws + 65273856);  /* alias qkv+attn (dead then) */
  float*          part_f = (float*)(ws + 116391936);          /* dedicated tail, 2.15 MB */
  float* dout = (float*)d_out;

  /* fused prep: weights -> bf16, pad rows -> 0 */
  convert_all<<<(NQ_ALL + 255) / 256, 256, 0, stream>>>(
      (const float4*)inw, (const float4*)outw, (const float4*)w1, (const float4*)w2,
      (ushort4*)wqkv_b, (ushort4*)wout_b, (ushort4*)w1_b, (ushort4*)w2_b,
      (ushort4*)(xw_b + (size_t)M_TOT * 768), (ushort4*)(attn_b + (size_t)M_TOT * 768));

  /* LN1 (+ implicit transpose of x) + special rows */
  ln1_all<<<dim3(65, 8), 256, 0, stream>>>(x, ctx, regs, ln1g, ln1b, xw_b);

  /* QKV: 128x128, NBUF=2, (256,4) -> 4 blocks/CU */
  gemm_bt<0, 768, 2304, 2><<<dim3(2304 / BN, M_PAD / BM), 256, 0, stream>>>(
      xw_b, wqkv_b, inb, nullptr, nullptr, nullptr, qkv_b);

  /* attention: feat (32 rows/block, group-parallel softmax) + special partials */
  attn_all<<<dim3(32 + NCHUNK, 12, 8), 256, 0, stream>>>(qkv_b, attn_b, part_f);
  attn_comb<<<dim3(5, 12, 8), 64, 0, stream>>>(part_f, attn_b);

  /* out-proj + residual -> h1 (fp32): grid-limited (390) -> NBUF=4 deep */
  gemm_bt<1, 768, 768, 4><<<dim3(768 / BN, M_PAD / BM), 256, 0, stream>>>(
      attn_b, wout_b, outbi, xw_b, nullptr, h1_f, nullptr);

  /* LN2 */
  ln2_kernel<<<M_PAD / 4, 256, 0, stream>>>(h1_f, ln2g, ln2b, ln2o_b);

  /* FF1 + fast GELU: 128x256, 8 waves, NBUF=3 counted-vmcnt (780 blocks, 2/CU) */
  gemm_bn256<2, 768, 3072><<<dim3(3072 / 256, M_PAD / BM), 512, 0, stream>>>(
      ln2o_b, w1_b, b1, ffm_b);

  /* FF2 + h1 residual + fused transpose-scatter straight to dout */
  gemm_ff2scat<<<dim3(768 / BN, M_PAD / BM), 256, 0, stream>>>(
      ffm_b, w2_b, b2, h1_f, dout);
}